// Round 7
// baseline (511.876 us; speedup 1.0000x reference)
//
#include <hip/hip_runtime.h>
#include <hip/hip_bf16.h>
#include <hip/hip_cooperative_groups.h>

#define FEAT 64
#define CHUNK 2048   // edges per hist/scatter chunk
#define MAX_NB 1024  // max buckets (256 nodes/bucket -> N <= 262144)
#define MEGA_GRID 512

namespace cg = cooperative_groups;

typedef __attribute__((ext_vector_type(8))) short bf16x8;
typedef __attribute__((ext_vector_type(4))) float f32x4;
typedef __attribute__((ext_vector_type(2))) float f32x2;

// ---------- bf16 helpers ----------
__device__ __forceinline__ float bflo2f(unsigned int u) {
    union { unsigned int u; float f; } v; v.u = u << 16; return v.f;
}
__device__ __forceinline__ float bfhi2f(unsigned int u) {
    union { unsigned int u; float f; } v; v.u = u & 0xffff0000u; return v.f;
}
__device__ __forceinline__ unsigned short f2bf(float f) {
    union { float f; unsigned int u; } v; v.f = f;
    unsigned int u = v.u;
    u += 0x7fffu + ((u >> 16) & 1u);   // round-to-nearest-even
    return (unsigned short)(u >> 16);
}
__device__ __forceinline__ f32x2 bfpair(unsigned int u) {
    f32x2 r; r.x = bflo2f(u & 0xffffu); r.y = bfhi2f(u); return r;
}

// ================= CSR build phases (shared by mega + fallback) =================

// prep: one element i — weight conversion (i<16642) + x->bf16 (fp32 path)
__device__ __forceinline__ void phase_prep_elem(
    int i, int f0,
    const void* w1a, const void* w1r, const void* b1, const void* w2a,
    const void* w2r, const void* b2, const void* wl, const void* bl,
    float* wbuf, unsigned short* Wt,
    const void* x_in, unsigned short* x16, int n8) {
    if (i < 16642) {
        const void* src; int off;
        if      (i < 4096)  { src = w1a; off = i; }
        else if (i < 8192)  { src = w1r; off = i - 4096; }
        else if (i < 8256)  { src = b1;  off = i - 8192; }
        else if (i < 12352) { src = w2a; off = i - 8256; }
        else if (i < 16448) { src = w2r; off = i - 12352; }
        else if (i < 16512) { src = b2;  off = i - 16448; }
        else if (i < 16640) { src = wl;  off = i - 16512; }
        else                { src = bl;  off = i - 16640; }
        float v = f0 ? bflo2f(((const unsigned short*)src)[off])
                     : ((const float*)src)[off];
        wbuf[i] = v;
        unsigned short hv = f2bf(v);   // exact round-trip when input was bf16
        if (i < 4096)                      Wt[(off & 63) * 128 + (off >> 6)] = hv;
        else if (i < 8192)                 Wt[(off & 63) * 128 + 64 + (off >> 6)] = hv;
        else if (i >= 8256 && i < 12352)   Wt[8192 + (off & 63) * 128 + (off >> 6)] = hv;
        else if (i >= 12352 && i < 16448)  Wt[8192 + (off & 63) * 128 + 64 + (off >> 6)] = hv;
    }
    if (!f0 && i < n8) {
        float4 a = ((const float4*)x_in)[2 * i];
        float4 b = ((const float4*)x_in)[2 * i + 1];
        uint4 o;
        o.x = (unsigned int)f2bf(a.x) | ((unsigned int)f2bf(a.y) << 16);
        o.y = (unsigned int)f2bf(a.z) | ((unsigned int)f2bf(a.w) << 16);
        o.z = (unsigned int)f2bf(b.x) | ((unsigned int)f2bf(b.y) << 16);
        o.w = (unsigned int)f2bf(b.z) | ((unsigned int)f2bf(b.w) << 16);
        ((uint4*)x16)[i] = o;
    }
}

// p1: bucket histogram of chunk c (bucket = dst >> 8)
__device__ __forceinline__ void phase_hist_chunk(
    int c, int idx64, const int* __restrict__ ei32, int* __restrict__ hist,
    int E, int N, int NB, int EC, int* lh, int tid) {
    for (int i = tid; i < NB; i += 256) lh[i] = 0;
    __syncthreads();
    long base = (long)c * CHUNK;
    for (int j = 0; j < CHUNK / 256; ++j) {
        long e = base + j * 256 + tid;
        if (e < E) {
            int d = idx64 ? ei32[2 * ((long)E + e)] : ei32[(long)E + e];
            if ((unsigned)d < (unsigned)N) atomicAdd(&lh[d >> 8], 1);
        }
    }
    __syncthreads();
    for (int k = tid; k < NB; k += 256) hist[(long)k * EC + c] = lh[k];
    __syncthreads();
}

// scan1: block b scans 2048 elements of in -> out (local excl), emits blocksum
__device__ __forceinline__ void phase_scan1_block(
    int b, const int* __restrict__ in, int* __restrict__ out,
    int* __restrict__ bsum, int n, int tid, int* sh) {
    int base = b * 2048 + tid * 8;
    int v[8];
    int tsum = 0;
#pragma unroll
    for (int i = 0; i < 8; ++i) { v[i] = (base + i < n) ? in[base + i] : 0; tsum += v[i]; }
    int lane = tid & 63;
    int x = tsum;
#pragma unroll
    for (int off = 1; off < 64; off <<= 1) {
        int y = __shfl_up(x, off);
        if (lane >= off) x += y;
    }
    int wave = tid >> 6;
    if (lane == 63) sh[wave] = x;
    __syncthreads();
    int woff = 0;
#pragma unroll
    for (int w = 0; w < 4; ++w) if (w < wave) woff += sh[w];
    int run = woff + x - tsum;
#pragma unroll
    for (int i = 0; i < 8; ++i) { if (base + i < n) out[base + i] = run; run += v[i]; }
    if (tid == 255) bsum[b] = woff + x;
    __syncthreads();
}

// scan3: block b adds its uniform block prefix
__device__ __forceinline__ void phase_scan3_block(
    int b, int* __restrict__ out, const int* __restrict__ bsum,
    int n, int tid, int* sh) {
    int s = 0;
    for (int q = tid; q < b; q += 256) s += bsum[q];
#pragma unroll
    for (int off = 32; off > 0; off >>= 1) s += __shfl_down(s, off);
    int lane = tid & 63, wave = tid >> 6;
    if (lane == 0) sh[wave] = s;
    __syncthreads();
    if (tid == 0) sh[4] = sh[0] + sh[1] + sh[2] + sh[3];
    __syncthreads();
    int pre = sh[4];
    int base = b * 2048;
#pragma unroll
    for (int k = 0; k < 8; ++k) {
        int i = base + k * 256 + tid;
        if (i < n) out[i] += pre;
    }
    __syncthreads();
}

// p3: scatter chunk c's edges into bucket-major bkt; packed = src | (dst&255)<<20
__device__ __forceinline__ void phase_p3_chunk(
    int c, int idx64, const int* __restrict__ ei32, const int* __restrict__ hscan,
    int* __restrict__ bkt, int E, int N, int NB, int EC, int* lh, int tid) {
    for (int i = tid; i < NB; i += 256) lh[i] = 0;
    __syncthreads();
    long base = (long)c * CHUNK;
    for (int j = 0; j < CHUNK / 256; ++j) {
        long e = base + j * 256 + tid;
        if (e < E) {
            int s = idx64 ? ei32[2 * e]             : ei32[e];
            int d = idx64 ? ei32[2 * ((long)E + e)] : ei32[(long)E + e];
            if ((unsigned)d < (unsigned)N) {
                if ((unsigned)s >= (unsigned)N) s = 0;   // clamp (memory safety)
                int k = d >> 8;
                int r = atomicAdd(&lh[k], 1);
                bkt[hscan[(long)k * EC + c] + r] = s | ((d & 255) << 20);
            }
        }
    }
    __syncthreads();
}

// p4: finalize bucket k -> per-node offs/cnt + node-sorted srcs
__device__ __forceinline__ void phase_p4_bucket(
    int k, const int* __restrict__ bkt, const int* __restrict__ hscan,
    const int* __restrict__ hist, int* __restrict__ offs, int* __restrict__ cnt,
    int* __restrict__ srcs, int N, int NB, int EC, int* sh, int tid) {
    int* lc = sh; int* lheads = sh + 256; int* wsum = sh + 512;
    int start = hscan[(long)k * EC];
    int end = (k + 1 < NB) ? hscan[(long)(k + 1) * EC]
                           : (hscan[(long)NB * EC - 1] + hist[(long)NB * EC - 1]);
    lc[tid] = 0;
    __syncthreads();
    for (int e = start + tid; e < end; e += 256)
        atomicAdd(&lc[(bkt[e] >> 20) & 255], 1);
    __syncthreads();
    int cv = lc[tid];
    int lane = tid & 63, wave = tid >> 6;
    int x = cv;
#pragma unroll
    for (int off = 1; off < 64; off <<= 1) {
        int y = __shfl_up(x, off);
        if (lane >= off) x += y;
    }
    if (lane == 63) wsum[wave] = x;
    __syncthreads();
    int woff = 0;
#pragma unroll
    for (int w = 0; w < 4; ++w) if (w < wave) woff += wsum[w];
    int excl = woff + x - cv;
    int gnode = k * 256 + tid;
    if (gnode < N) { offs[gnode] = start + excl; cnt[gnode] = cv; }
    lheads[tid] = excl;
    __syncthreads();
    for (int e = start + tid; e < end; e += 256) {
        int p = bkt[e];
        int d8 = (p >> 20) & 255;
        int pos = start + atomicAdd(&lheads[d8], 1);
        srcs[pos] = p & 0xFFFFF;
    }
    __syncthreads();
}

// ================= cooperative mega-kernel: all CSR phases, 4 grid syncs =================
__global__ __launch_bounds__(256) void csr_mega_kernel(
    const unsigned short* __restrict__ xh, const int* __restrict__ ei32,
    const void* w1a, const void* w1r, const void* b1, const void* w2a,
    const void* w2r, const void* b2, const void* wl, const void* bl,
    float* __restrict__ wbuf, unsigned short* __restrict__ Wt, int* __restrict__ flags,
    const void* __restrict__ x_in, unsigned short* __restrict__ x16, int n8, int pMax,
    int* __restrict__ hist, int* __restrict__ hscan, int* __restrict__ bsum,
    int* __restrict__ offs, int* __restrict__ cnt, int* __restrict__ bkt,
    int* __restrict__ srcs,
    int E, int N, int NB, int EC, int HN, int sB) {
    cg::grid_group grid = cg::this_grid();
    __shared__ int sh[MAX_NB];
    int tid = threadIdx.x;

    // dtype + index-width self-detect (per block; identical data -> identical result)
    if (tid == 0) { sh[0] = 0; sh[1] = 0; }
    __syncthreads();
    if (ei32[tid * 2 + 1] != 0) atomicAdd(&sh[0], 1);
    { unsigned short h = xh[tid * 2]; int e = (h >> 7) & 0xFF;
      if (e >= 110 && e <= 132) atomicAdd(&sh[1], 1); }
    __syncthreads();
    int idx64 = (sh[0] < 8) ? 1 : 0;
    int f0 = (sh[1] >= 128) ? 1 : 0;
    if (blockIdx.x == 0 && tid == 0) { flags[0] = f0; flags[1] = idx64; }
    __syncthreads();

    // Phase 0: prep (weights + x conversion) — no grid dependency
    for (int i = blockIdx.x * 256 + tid; i < pMax; i += gridDim.x * 256)
        phase_prep_elem(i, f0, w1a, w1r, b1, w2a, w2r, b2, wl, bl,
                        wbuf, Wt, x_in, x16, n8);

    // Phase A: per-chunk bucket histogram
    for (int c = blockIdx.x; c < EC; c += gridDim.x)
        phase_hist_chunk(c, idx64, ei32, hist, E, N, NB, EC, sh, tid);
    grid.sync();

    // Phase B: scan1 over HN
    if (blockIdx.x < sB) phase_scan1_block(blockIdx.x, hist, hscan, bsum, HN, tid, sh);
    grid.sync();

    // Phase C: scan3 (block prefixes)
    if (blockIdx.x < sB) phase_scan3_block(blockIdx.x, hscan, bsum, HN, tid, sh);
    grid.sync();

    // Phase D: scatter to bucket-major bkt
    for (int c = blockIdx.x; c < EC; c += gridDim.x)
        phase_p3_chunk(c, idx64, ei32, hscan, bkt, E, N, NB, EC, sh, tid);
    grid.sync();

    // Phase E: per-bucket CSR finalize
    for (int k = blockIdx.x; k < NB; k += gridDim.x)
        phase_p4_bucket(k, bkt, hscan, hist, offs, cnt, srcs, N, NB, EC, sh, tid);
}

// ================= fallback kernels (plain launches; R5-equivalent) =================
__global__ __launch_bounds__(256) void fb_prep_kernel(
    const unsigned short* __restrict__ xh, const int* __restrict__ ei32,
    const void* w1a, const void* w1r, const void* b1, const void* w2a,
    const void* w2r, const void* b2, const void* wl, const void* bl,
    float* __restrict__ wbuf, unsigned short* __restrict__ Wt, int* __restrict__ flags,
    const void* __restrict__ x_in, unsigned short* __restrict__ x16, int n8, int pMax) {
    __shared__ int c0, c1;
    int tid = threadIdx.x;
    if (tid == 0) { c0 = 0; c1 = 0; }
    __syncthreads();
    if (ei32[tid * 2 + 1] != 0) atomicAdd(&c0, 1);
    { unsigned short h = xh[tid * 2]; int e = (h >> 7) & 0xFF;
      if (e >= 110 && e <= 132) atomicAdd(&c1, 1); }
    __syncthreads();
    int f0 = (c1 >= 128) ? 1 : 0;
    if (blockIdx.x == 0 && tid == 0) { flags[0] = f0; flags[1] = (c0 < 8) ? 1 : 0; }
    int i = blockIdx.x * 256 + tid;
    if (i < pMax)
        phase_prep_elem(i, f0, w1a, w1r, b1, w2a, w2r, b2, wl, bl,
                        wbuf, Wt, x_in, x16, n8);
}
__global__ __launch_bounds__(256) void fb_hist_kernel(
    const int* __restrict__ ei32, int* __restrict__ hist,
    int E, int N, int NB, int EC, const int* __restrict__ flags) {
    __shared__ int sh[MAX_NB];
    phase_hist_chunk(blockIdx.x, flags[1], ei32, hist, E, N, NB, EC, sh, threadIdx.x);
}
__global__ __launch_bounds__(256) void fb_scan1_kernel(
    const int* __restrict__ in, int* __restrict__ out, int* __restrict__ bsum, int n) {
    __shared__ int sh[8];
    phase_scan1_block(blockIdx.x, in, out, bsum, n, threadIdx.x, sh);
}
__global__ __launch_bounds__(256) void fb_scan3_kernel(
    int* __restrict__ out, const int* __restrict__ bsum, int n) {
    __shared__ int sh[8];
    phase_scan3_block(blockIdx.x, out, bsum, n, threadIdx.x, sh);
}
__global__ __launch_bounds__(256) void fb_p3_kernel(
    const int* __restrict__ ei32, const int* __restrict__ hscan, int* __restrict__ bkt,
    int E, int N, int NB, int EC, const int* __restrict__ flags) {
    __shared__ int sh[MAX_NB];
    phase_p3_chunk(blockIdx.x, flags[1], ei32, hscan, bkt, E, N, NB, EC, sh, threadIdx.x);
}
__global__ __launch_bounds__(256) void fb_p4_kernel(
    const int* __restrict__ bkt, const int* __restrict__ hscan,
    const int* __restrict__ hist, int* __restrict__ offs, int* __restrict__ cnt,
    int* __restrict__ srcs, int N, int NB, int EC) {
    __shared__ int sh[520];
    phase_p4_bucket(blockIdx.x, bkt, hscan, hist, offs, cnt, srcs, N, NB, EC, sh, threadIdx.x);
}

// ---------- FUSED: aggregate + MFMA SAGE GEMM (R5-exact, best measured) ----------
__global__ __launch_bounds__(256) void sage_fused_kernel(
    const void* __restrict__ feat_raw, const unsigned short* __restrict__ feat_ws,
    const int* __restrict__ srcs, const int* __restrict__ offs,
    const int* __restrict__ cnt,
    const unsigned short* __restrict__ Wt, const float* __restrict__ bias,
    unsigned short* __restrict__ out16, int N,
    const float* __restrict__ wl, const float* __restrict__ bl,
    void* __restrict__ out_final, const int* __restrict__ flags, int sel) {

    const unsigned short* feat16 =
        (sel && !flags[0]) ? feat_ws : (const unsigned short*)feat_raw;

    __shared__ unsigned short A_l[64][72];    // agg half only; reused as C staging
    __shared__ unsigned short B_l[64][136];   // Wt[n][k]

    int tid = threadIdx.x;
    int blk = blockIdx.x;

#pragma unroll
    for (int i = 0; i < 4; ++i) {
        int ch = tid + i * 256;
        int n = ch >> 4, kc = ch & 15;
        *(uint4*)&B_l[n][kc * 8] = *(const uint4*)(Wt + n * 128 + kc * 8);
    }

    int lane = tid & 63;
    int wave = tid >> 6;
    int g = lane >> 3;
    int li = lane & 7;

    for (int pass = 0; pass < 2; ++pass) {
        int r = pass * 32 + wave * 8 + g;
        int node = blk * 64 + r;
        f32x2 a0 = {0.f, 0.f}, a1 = a0, a2 = a0, a3 = a0;
        int deg = 0;
        if (node < N) {
            int start = offs[node];
            deg = cnt[node];
            int j = 0;
            for (; j + 4 <= deg; j += 4) {
                int s0 = srcs[start + j];
                int s1 = srcs[start + j + 1];
                int s2 = srcs[start + j + 2];
                int s3 = srcs[start + j + 3];
                uint4 u0 = *(const uint4*)(feat16 + (size_t)s0 * FEAT + 8 * li);
                uint4 u1 = *(const uint4*)(feat16 + (size_t)s1 * FEAT + 8 * li);
                uint4 u2 = *(const uint4*)(feat16 + (size_t)s2 * FEAT + 8 * li);
                uint4 u3 = *(const uint4*)(feat16 + (size_t)s3 * FEAT + 8 * li);
                a0 += bfpair(u0.x); a1 += bfpair(u0.y); a2 += bfpair(u0.z); a3 += bfpair(u0.w);
                a0 += bfpair(u1.x); a1 += bfpair(u1.y); a2 += bfpair(u1.z); a3 += bfpair(u1.w);
                a0 += bfpair(u2.x); a1 += bfpair(u2.y); a2 += bfpair(u2.z); a3 += bfpair(u2.w);
                a0 += bfpair(u3.x); a1 += bfpair(u3.y); a2 += bfpair(u3.z); a3 += bfpair(u3.w);
            }
            for (; j < deg; ++j) {
                int s = srcs[start + j];
                uint4 u = *(const uint4*)(feat16 + (size_t)s * FEAT + 8 * li);
                a0 += bfpair(u.x); a1 += bfpair(u.y); a2 += bfpair(u.z); a3 += bfpair(u.w);
            }
        }
        float inv = 1.0f / (float)(deg > 0 ? deg : 1);
        uint4 o;
        o.x = (unsigned)f2bf(a0.x * inv) | ((unsigned)f2bf(a0.y * inv) << 16);
        o.y = (unsigned)f2bf(a1.x * inv) | ((unsigned)f2bf(a1.y * inv) << 16);
        o.z = (unsigned)f2bf(a2.x * inv) | ((unsigned)f2bf(a2.y * inv) << 16);
        o.w = (unsigned)f2bf(a3.x * inv) | ((unsigned)f2bf(a3.y * inv) << 16);
        *(uint4*)&A_l[r][8 * li] = o;
    }
    __syncthreads();

    int r0 = wave * 16;
    int m = lane & 15, quad = lane >> 4;

    int arow = blk * 64 + r0 + m;
    if (arow >= N) arow = 0;
    const unsigned short* rootp = feat16 + (size_t)arow * FEAT + quad * 8;

    f32x4 acc0 = {0.f, 0.f, 0.f, 0.f};
    f32x4 acc1 = acc0, acc2 = acc0, acc3 = acc0;

#pragma unroll
    for (int k0 = 0; k0 < 128; k0 += 32) {
        bf16x8 a;
        if (k0 < 64) a = *(const bf16x8*)&A_l[r0 + m][k0 + quad * 8];
        else         a = *(const bf16x8*)(rootp + (k0 - 64));
        bf16x8 b0 = *(const bf16x8*)&B_l[ 0 + m][k0 + quad * 8];
        bf16x8 b1 = *(const bf16x8*)&B_l[16 + m][k0 + quad * 8];
        bf16x8 b2 = *(const bf16x8*)&B_l[32 + m][k0 + quad * 8];
        bf16x8 b3 = *(const bf16x8*)&B_l[48 + m][k0 + quad * 8];
        acc0 = __builtin_amdgcn_mfma_f32_16x16x32_bf16(a, b0, acc0, 0, 0, 0);
        acc1 = __builtin_amdgcn_mfma_f32_16x16x32_bf16(a, b1, acc1, 0, 0, 0);
        acc2 = __builtin_amdgcn_mfma_f32_16x16x32_bf16(a, b2, acc2, 0, 0, 0);
        acc3 = __builtin_amdgcn_mfma_f32_16x16x32_bf16(a, b3, acc3, 0, 0, 0);
    }
    __syncthreads();   // done reading A_l; reuse as C staging

#pragma unroll
    for (int c = 0; c < 4; ++c) {
        f32x4 av = (c == 0) ? acc0 : (c == 1) ? acc1 : (c == 2) ? acc2 : acc3;
        float bv = bias[c * 16 + m];
#pragma unroll
        for (int reg = 0; reg < 4; ++reg) {
            float v = fmaxf(av[reg] + bv, 0.f);
            A_l[r0 + quad * 4 + reg][c * 16 + m] = f2bf(v);
        }
    }
    __syncthreads();

    if (out16) {
#pragma unroll
        for (int i = 0; i < 2; ++i) {
            int ch = tid + i * 256;
            int r = ch >> 3, c = ch & 7;
            int row = blk * 64 + r;
            if (row < N)
                ((uint4*)(out16 + (size_t)row * FEAT))[c] = *(const uint4*)&A_l[r][c * 8];
        }
    }

    if (wl) {
        int r = tid >> 2, part = tid & 3;
        int row = blk * 64 + r;
        if (row < N) {
            float p0 = 0.f, p1 = 0.f;
#pragma unroll
            for (int j = 0; j < 16; ++j) {
                int f = part * 16 + j;
                float v = bflo2f(A_l[r][f]);
                p0 += v * wl[f * 2 + 0];
                p1 += v * wl[f * 2 + 1];
            }
            p0 += __shfl_down(p0, 2, 4); p0 += __shfl_down(p0, 1, 4);
            p1 += __shfl_down(p1, 2, 4); p1 += __shfl_down(p1, 1, 4);
            if (part == 0) {
                p0 += bl[0];
                p1 += bl[1];
                if (flags[0]) {
                    unsigned int o = ((unsigned int)f2bf(p1) << 16) | (unsigned int)f2bf(p0);
                    ((unsigned int*)out_final)[row] = o;
                } else {
                    ((float2*)out_final)[row] = make_float2(p0, p1);
                }
            }
        }
    }
}

extern "C" void kernel_launch(void* const* d_in, const int* in_sizes, int n_in,
                              void* d_out, int out_size, void* d_ws, size_t ws_size,
                              hipStream_t stream) {
    const void* x_in = d_in[0];
    const int*  ei32 = (const int*)d_in[1];
    const unsigned short* xh = (const unsigned short*)x_in;
    const void* w1a = d_in[2]; const void* w1r = d_in[3];
    const void* b1p = d_in[4]; const void* w2a = d_in[5];
    const void* w2r = d_in[6]; const void* b2p = d_in[7];
    const void* wlp = d_in[8]; const void* blp = d_in[9];

    int N = in_sizes[0] / FEAT;
    int E = in_sizes[1] / 2;
    int NB = (N + 255) >> 8;
    int EC = (E + CHUNK - 1) / CHUNK;
    int HN = NB * EC;
    int sB = (HN + 2047) / 2048;

    // workspace layout (R5)
    unsigned short* x16   = (unsigned short*)d_ws;                 // N*64 bf16
    unsigned short* h16   = x16 + (size_t)N * FEAT;                // N*64
    unsigned short* Wt    = h16 + (size_t)N * FEAT;                // 16384
    float*          wbuf  = (float*)(Wt + 16384);                  // 16704
    int*            hist  = (int*)(wbuf + 16704);                  // HN
    int*            hscan = hist + HN;                             // HN
    int*            bsum  = hscan + HN;                            // <=1024
    int*            flags = bsum + 1024;                           // 16
    int*            offs  = flags + 16;                            // N
    int*            cnt   = offs + N;                              // N
    int*            bkt   = cnt + N;                               // E
    int*            srcs  = bkt + E;                               // E

    float* b1_32 = wbuf + 8192;
    float* b2_32 = wbuf + 16448;
    float* wl32  = wbuf + 16512;
    float* bl32  = wbuf + 16640;

    int n8 = N * FEAT / 8;
    int pMax = (n8 > 16642) ? n8 : 16642;

    // --- CSR build: cooperative mega-kernel (4 grid syncs), else R5 fallback ---
    bool coop = false;
    int occ = 0;
    if (hipOccupancyMaxActiveBlocksPerMultiprocessor(&occ, csr_mega_kernel, 256, 0)
            == hipSuccess && occ >= 2) {
        void* args[] = {
            (void*)&xh, (void*)&ei32,
            (void*)&w1a, (void*)&w1r, (void*)&b1p, (void*)&w2a,
            (void*)&w2r, (void*)&b2p, (void*)&wlp, (void*)&blp,
            (void*)&wbuf, (void*)&Wt, (void*)&flags,
            (void*)&x_in, (void*)&x16, (void*)&n8, (void*)&pMax,
            (void*)&hist, (void*)&hscan, (void*)&bsum,
            (void*)&offs, (void*)&cnt, (void*)&bkt, (void*)&srcs,
            (void*)&E, (void*)&N, (void*)&NB, (void*)&EC, (void*)&HN, (void*)&sB };
        if (hipLaunchCooperativeKernel(csr_mega_kernel, dim3(MEGA_GRID), dim3(256),
                                       args, 0, stream) == hipSuccess)
            coop = true;
    }
    if (!coop) {
        int pBlocks = (pMax + 255) / 256;
        fb_prep_kernel<<<pBlocks, 256, 0, stream>>>(
            xh, ei32, w1a, w1r, b1p, w2a, w2r, b2p, wlp, blp,
            wbuf, Wt, flags, x_in, x16, n8, pMax);
        fb_hist_kernel<<<EC, 256, 0, stream>>>(ei32, hist, E, N, NB, EC, flags);
        fb_scan1_kernel<<<sB, 256, 0, stream>>>(hist, hscan, bsum, HN);
        fb_scan3_kernel<<<sB, 256, 0, stream>>>(hscan, bsum, HN);
        fb_p3_kernel<<<EC, 256, 0, stream>>>(ei32, hscan, bkt, E, N, NB, EC, flags);
        fb_p4_kernel<<<NB, 256, 0, stream>>>(bkt, hscan, hist, offs, cnt, srcs, N, NB, EC);
    }

    int gBlocks = (N + 63) / 64;

    // layer 1: fused aggregate + GEMM (x -> h16)
    sage_fused_kernel<<<gBlocks, 256, 0, stream>>>(
        x_in, x16, srcs, offs, cnt, Wt, b1_32, h16, N,
        nullptr, nullptr, nullptr, flags, 1);

    // layer 2: fused aggregate + GEMM + final projection
    sage_fused_kernel<<<gBlocks, 256, 0, stream>>>(
        h16, h16, srcs, offs, cnt, Wt + 8192, b2_32, nullptr, N,
        wl32, bl32, d_out, flags, 0);
}

// Round 8
// 243.703 us; speedup vs baseline: 2.1004x; 2.1004x over previous
//
#include <hip/hip_runtime.h>
#include <hip/hip_bf16.h>

#define FEAT 64
#define CHUNK 8192   // edges per P1/P3 chunk (196 chunks; ~21 edges/bucket/chunk -> low bkt write-amp)
#define MAX_NB 1024  // max buckets (256 nodes/bucket -> N <= 262144)

typedef __attribute__((ext_vector_type(8))) short bf16x8;
typedef __attribute__((ext_vector_type(4))) float f32x4;
typedef __attribute__((ext_vector_type(2))) float f32x2;

// ---------- bf16 helpers ----------
__device__ __forceinline__ float bflo2f(unsigned int u) {
    union { unsigned int u; float f; } v; v.u = u << 16; return v.f;
}
__device__ __forceinline__ float bfhi2f(unsigned int u) {
    union { unsigned int u; float f; } v; v.u = u & 0xffff0000u; return v.f;
}
__device__ __forceinline__ unsigned short f2bf(float f) {
    union { float f; unsigned int u; } v; v.f = f;
    unsigned int u = v.u;
    u += 0x7fffu + ((u >> 16) & 1u);   // round-to-nearest-even
    return (unsigned short)(u >> 16);
}
__device__ __forceinline__ f32x2 bfpair(unsigned int u) {
    f32x2 r; r.x = bflo2f(u & 0xffffu); r.y = bfhi2f(u); return r;
}

// ---------- 0. prep + P1 merged: role-split grid ----------
// blocks [0, pB): dtype detect + weight conversion + x conversion
//   (block 0 additionally zeroes the scan lookback flags for this iteration)
// blocks [pB, pB+EC): per-chunk bucket histogram (bucket = dst >> 8)
__global__ __launch_bounds__(256) void prep_p1_kernel(
    const unsigned short* __restrict__ xh, const int* __restrict__ ei32,
    const void* __restrict__ w1a, const void* __restrict__ w1r,
    const void* __restrict__ b1,  const void* __restrict__ w2a,
    const void* __restrict__ w2r, const void* __restrict__ b2,
    const void* __restrict__ wl,  const void* __restrict__ bl,
    float* __restrict__ wbuf, unsigned short* __restrict__ Wt,
    int* __restrict__ flags, const void* __restrict__ x_in,
    unsigned short* __restrict__ x16, int n8,
    int* __restrict__ hist, int* __restrict__ bflag, int sB,
    int E, int N, int NB, int EC, int pB) {
    __shared__ int lh[MAX_NB];
    __shared__ int cnt_bf, cnt_nz;
    int tid = threadIdx.x;

    if (blockIdx.x >= pB) {
        // ---- P1 role: histogram of chunk c (self-detect int64) ----
        int c = blockIdx.x - pB;
        if (tid == 0) cnt_nz = 0;
        for (int i = tid; i < NB; i += 256) lh[i] = 0;
        __syncthreads();
        if (ei32[tid * 2 + 1] != 0) atomicAdd(&cnt_nz, 1);
        __syncthreads();
        int idx64 = (cnt_nz < 8) ? 1 : 0;
        long base = (long)c * CHUNK;
#pragma unroll 4
        for (int j = 0; j < CHUNK / 256; ++j) {
            long e = base + j * 256 + tid;
            if (e < E) {
                int d = idx64 ? ei32[2 * ((long)E + e)] : ei32[(long)E + e];
                if ((unsigned)d < (unsigned)N)
                    atomicAdd(&lh[d >> 8], 1);
            }
        }
        __syncthreads();
        for (int k = tid; k < NB; k += 256) hist[(long)k * EC + c] = lh[k];
        return;
    }

    // ---- prep role ----
    if (tid == 0) { cnt_bf = 0; cnt_nz = 0; }
    __syncthreads();
    unsigned short h = xh[tid * 2];
    int e = (h >> 7) & 0xFF;
    if (e >= 110 && e <= 132) atomicAdd(&cnt_bf, 1);
    if (ei32[tid * 2 + 1] != 0) atomicAdd(&cnt_nz, 1);
    __syncthreads();
    int f0 = (cnt_bf >= 128) ? 1 : 0;
    if (blockIdx.x == 0) {
        if (tid == 0) {
            flags[0] = f0;
            flags[1] = (cnt_nz < 8) ? 1 : 0;
        }
        if (tid < sB) bflag[tid] = 0;   // reset scan lookback flags each iteration
    }
    int i = blockIdx.x * 256 + tid;
    // weights (blocks 0..65): wbuf f32 + Wt bf16-transposed
    if (i < 16642) {
        const void* src; int off;
        if      (i < 4096)  { src = w1a; off = i; }
        else if (i < 8192)  { src = w1r; off = i - 4096; }
        else if (i < 8256)  { src = b1;  off = i - 8192; }
        else if (i < 12352) { src = w2a; off = i - 8256; }
        else if (i < 16448) { src = w2r; off = i - 12352; }
        else if (i < 16512) { src = b2;  off = i - 16448; }
        else if (i < 16640) { src = wl;  off = i - 16512; }
        else                { src = bl;  off = i - 16640; }
        float v = f0 ? bflo2f(((const unsigned short*)src)[off])
                     : ((const float*)src)[off];
        wbuf[i] = v;
        unsigned short hv = f2bf(v);   // exact round-trip when input was bf16
        if (i < 4096)                      Wt[(off & 63) * 128 + (off >> 6)] = hv;
        else if (i < 8192)                 Wt[(off & 63) * 128 + 64 + (off >> 6)] = hv;
        else if (i >= 8256 && i < 12352)   Wt[8192 + (off & 63) * 128 + (off >> 6)] = hv;
        else if (i >= 12352 && i < 16448)  Wt[8192 + (off & 63) * 128 + 64 + (off >> 6)] = hv;
    }
    // x -> bf16 (fp32 path only)
    if (!f0 && i < n8) {
        float4 a = ((const float4*)x_in)[2 * i];
        float4 b = ((const float4*)x_in)[2 * i + 1];
        uint4 o;
        o.x = (unsigned int)f2bf(a.x) | ((unsigned int)f2bf(a.y) << 16);
        o.y = (unsigned int)f2bf(a.z) | ((unsigned int)f2bf(a.w) << 16);
        o.z = (unsigned int)f2bf(b.x) | ((unsigned int)f2bf(b.y) << 16);
        o.w = (unsigned int)f2bf(b.z) | ((unsigned int)f2bf(b.w) << 16);
        ((uint4*)x16)[i] = o;
    }
}

// ---------- single-pass scan with decoupled lookback ----------
// Block b scans elements [b*2048, +2048). Publishes its total via device-scope
// atomics (bsum value then bflag release); thread 0 spins on predecessors'
// flags (device-scope atomicAdd reads — required across non-coherent XCD L2s,
// G16). sB = 38 blocks << 256 CUs: all co-resident, no deadlock. Flags zeroed
// by prep_p1 block 0 (prior launch) each iteration.
__global__ __launch_bounds__(256) void scan_kernel(
    const int* __restrict__ in, int* __restrict__ out,
    int* __restrict__ bsum, int* __restrict__ bflag, int n) {
    int b = blockIdx.x, tid = threadIdx.x;
    int base = b * 2048 + tid * 8;
    int v[8];
    int tsum = 0;
#pragma unroll
    for (int i = 0; i < 8; ++i) {
        v[i] = (base + i < n) ? in[base + i] : 0;
        tsum += v[i];
    }
    int lane = tid & 63;
    int x = tsum;
#pragma unroll
    for (int off = 1; off < 64; off <<= 1) {
        int y = __shfl_up(x, off);
        if (lane >= off) x += y;
    }
    __shared__ int wsum[4];
    __shared__ int spre;
    int wave = tid >> 6;
    if (lane == 63) wsum[wave] = x;
    __syncthreads();
    // publish this block's total (device scope: atomicExch, then flag)
    if (tid == 255) {
        int total = 0;
#pragma unroll
        for (int w = 0; w < 4; ++w) total += wsum[w];
        atomicExch(&bsum[b], total);
        __threadfence();              // total visible before flag
        atomicExch(&bflag[b], 1);
    }
    // lookback: thread 0 accumulates predecessors' totals
    if (tid == 0) {
        int pre = 0;
        for (int q = 0; q < b; ++q) {
            while (atomicAdd(&bflag[q], 0) == 0) { }
            pre += atomicAdd(&bsum[q], 0);
        }
        spre = pre;
    }
    __syncthreads();
    int woff = spre;
#pragma unroll
    for (int w = 0; w < 4; ++w) if (w < wave) woff += wsum[w];
    int run = woff + x - tsum;
#pragma unroll
    for (int i = 0; i < 8; ++i) {
        if (base + i < n) out[base + i] = run;
        run += v[i];
    }
}

// ---------- P3: scatter packed edges into bucket-major order ----------
// packed = src | ((dst & 255) << 20)   (requires N < 2^20)
__global__ __launch_bounds__(256) void p3_scatter_kernel(
    const int* __restrict__ ei32, const int* __restrict__ hscan,
    int* __restrict__ bkt, int E, int N, int NB, int EC,
    const int* __restrict__ flags) {
    __shared__ int lh[MAX_NB];
    int tid = threadIdx.x, c = blockIdx.x;
    for (int i = tid; i < NB; i += 256) lh[i] = 0;
    __syncthreads();
    int idx64 = flags[1];
    long base = (long)c * CHUNK;
#pragma unroll 4
    for (int j = 0; j < CHUNK / 256; ++j) {
        long e = base + j * 256 + tid;
        if (e < E) {
            int s = idx64 ? ei32[2 * e]             : ei32[e];
            int d = idx64 ? ei32[2 * ((long)E + e)] : ei32[(long)E + e];
            if ((unsigned)d < (unsigned)N) {
                if ((unsigned)s >= (unsigned)N) s = 0;   // clamp (memory safety)
                int k = d >> 8;
                int r = atomicAdd(&lh[k], 1);
                bkt[hscan[(long)k * EC + c] + r] = s | ((d & 255) << 20);
            }
        }
    }
}

// ---------- P4: per-bucket CSR finalize ----------
__global__ __launch_bounds__(256) void p4_build_kernel(
    const int* __restrict__ bkt, const int* __restrict__ hscan, const int* __restrict__ hist,
    int* __restrict__ offs, int* __restrict__ cnt, int* __restrict__ srcs,
    int E, int N, int NB, int EC) {
    int k = blockIdx.x, tid = threadIdx.x;
    int start = hscan[(long)k * EC];
    int end = (k + 1 < NB) ? hscan[(long)(k + 1) * EC]
                           : (hscan[(long)NB * EC - 1] + hist[(long)NB * EC - 1]);
    __shared__ int lc[256], lheads[256], wsum[4];
    lc[tid] = 0;
    __syncthreads();
    for (int e = start + tid; e < end; e += 256)
        atomicAdd(&lc[(bkt[e] >> 20) & 255], 1);
    __syncthreads();
    int cv = lc[tid];
    int lane = tid & 63, wave = tid >> 6;
    int x = cv;
#pragma unroll
    for (int off = 1; off < 64; off <<= 1) {
        int y = __shfl_up(x, off);
        if (lane >= off) x += y;
    }
    if (lane == 63) wsum[wave] = x;
    __syncthreads();
    int woff = 0;
#pragma unroll
    for (int w = 0; w < 4; ++w) if (w < wave) woff += wsum[w];
    int excl = woff + x - cv;
    int gnode = k * 256 + tid;
    if (gnode < N) { offs[gnode] = start + excl; cnt[gnode] = cv; }
    lheads[tid] = excl;
    __syncthreads();
    for (int e = start + tid; e < end; e += 256) {
        int p = bkt[e];
        int d8 = (p >> 20) & 255;
        int pos = start + atomicAdd(&lheads[d8], 1);
        srcs[pos] = p & 0xFFFFF;
    }
}

// ---------- 5+6 FUSED: aggregate + MFMA SAGE GEMM (R5-exact, best measured) ----------
// R1 gather (single node per 8-lane group, srcs global broadcast, unroll-4) +
// root half read directly from global in the MFMA loop (no root staging;
// A_l [64][72]; LDS 26624 B). Gather is pinned at the 8-XCD feature-table
// replication floor (~82 MB L2-miss / layer) — measured invariant across
// R1/R2/R4/R5 structural variants.
__global__ __launch_bounds__(256) void sage_fused_kernel(
    const void* __restrict__ feat_raw, const unsigned short* __restrict__ feat_ws,
    const int* __restrict__ srcs, const int* __restrict__ offs,
    const int* __restrict__ cnt,
    const unsigned short* __restrict__ Wt, const float* __restrict__ bias,
    unsigned short* __restrict__ out16, int N,
    const float* __restrict__ wl, const float* __restrict__ bl,
    void* __restrict__ out_final, const int* __restrict__ flags, int sel) {

    const unsigned short* feat16 =
        (sel && !flags[0]) ? feat_ws : (const unsigned short*)feat_raw;

    __shared__ unsigned short A_l[64][72];    // agg half only; reused as C staging
    __shared__ unsigned short B_l[64][136];   // Wt[n][k]

    int tid = threadIdx.x;
    int blk = blockIdx.x;

#pragma unroll
    for (int i = 0; i < 4; ++i) {
        int ch = tid + i * 256;
        int n = ch >> 4, kc = ch & 15;
        *(uint4*)&B_l[n][kc * 8] = *(const uint4*)(Wt + n * 128 + kc * 8);
    }

    int lane = tid & 63;
    int wave = tid >> 6;
    int g = lane >> 3;
    int li = lane & 7;

    for (int pass = 0; pass < 2; ++pass) {
        int r = pass * 32 + wave * 8 + g;
        int node = blk * 64 + r;
        f32x2 a0 = {0.f, 0.f}, a1 = a0, a2 = a0, a3 = a0;
        int deg = 0;
        if (node < N) {
            int start = offs[node];
            deg = cnt[node];
            int j = 0;
            for (; j + 4 <= deg; j += 4) {
                int s0 = srcs[start + j];
                int s1 = srcs[start + j + 1];
                int s2 = srcs[start + j + 2];
                int s3 = srcs[start + j + 3];
                uint4 u0 = *(const uint4*)(feat16 + (size_t)s0 * FEAT + 8 * li);
                uint4 u1 = *(const uint4*)(feat16 + (size_t)s1 * FEAT + 8 * li);
                uint4 u2 = *(const uint4*)(feat16 + (size_t)s2 * FEAT + 8 * li);
                uint4 u3 = *(const uint4*)(feat16 + (size_t)s3 * FEAT + 8 * li);
                a0 += bfpair(u0.x); a1 += bfpair(u0.y); a2 += bfpair(u0.z); a3 += bfpair(u0.w);
                a0 += bfpair(u1.x); a1 += bfpair(u1.y); a2 += bfpair(u1.z); a3 += bfpair(u1.w);
                a0 += bfpair(u2.x); a1 += bfpair(u2.y); a2 += bfpair(u2.z); a3 += bfpair(u2.w);
                a0 += bfpair(u3.x); a1 += bfpair(u3.y); a2 += bfpair(u3.z); a3 += bfpair(u3.w);
            }
            for (; j < deg; ++j) {
                int s = srcs[start + j];
                uint4 u = *(const uint4*)(feat16 + (size_t)s * FEAT + 8 * li);
                a0 += bfpair(u.x); a1 += bfpair(u.y); a2 += bfpair(u.z); a3 += bfpair(u.w);
            }
        }
        float inv = 1.0f / (float)(deg > 0 ? deg : 1);
        uint4 o;
        o.x = (unsigned)f2bf(a0.x * inv) | ((unsigned)f2bf(a0.y * inv) << 16);
        o.y = (unsigned)f2bf(a1.x * inv) | ((unsigned)f2bf(a1.y * inv) << 16);
        o.z = (unsigned)f2bf(a2.x * inv) | ((unsigned)f2bf(a2.y * inv) << 16);
        o.w = (unsigned)f2bf(a3.x * inv) | ((unsigned)f2bf(a3.y * inv) << 16);
        *(uint4*)&A_l[r][8 * li] = o;
    }
    __syncthreads();

    int r0 = wave * 16;
    int m = lane & 15, quad = lane >> 4;

    int arow = blk * 64 + r0 + m;
    if (arow >= N) arow = 0;
    const unsigned short* rootp = feat16 + (size_t)arow * FEAT + quad * 8;

    f32x4 acc0 = {0.f, 0.f, 0.f, 0.f};
    f32x4 acc1 = acc0, acc2 = acc0, acc3 = acc0;

#pragma unroll
    for (int k0 = 0; k0 < 128; k0 += 32) {
        bf16x8 a;
        if (k0 < 64) a = *(const bf16x8*)&A_l[r0 + m][k0 + quad * 8];
        else         a = *(const bf16x8*)(rootp + (k0 - 64));
        bf16x8 b0 = *(const bf16x8*)&B_l[ 0 + m][k0 + quad * 8];
        bf16x8 b1 = *(const bf16x8*)&B_l[16 + m][k0 + quad * 8];
        bf16x8 b2 = *(const bf16x8*)&B_l[32 + m][k0 + quad * 8];
        bf16x8 b3 = *(const bf16x8*)&B_l[48 + m][k0 + quad * 8];
        acc0 = __builtin_amdgcn_mfma_f32_16x16x32_bf16(a, b0, acc0, 0, 0, 0);
        acc1 = __builtin_amdgcn_mfma_f32_16x16x32_bf16(a, b1, acc1, 0, 0, 0);
        acc2 = __builtin_amdgcn_mfma_f32_16x16x32_bf16(a, b2, acc2, 0, 0, 0);
        acc3 = __builtin_amdgcn_mfma_f32_16x16x32_bf16(a, b3, acc3, 0, 0, 0);
    }
    __syncthreads();   // done reading A_l; reuse as C staging

#pragma unroll
    for (int c = 0; c < 4; ++c) {
        f32x4 av = (c == 0) ? acc0 : (c == 1) ? acc1 : (c == 2) ? acc2 : acc3;
        float bv = bias[c * 16 + m];
#pragma unroll
        for (int reg = 0; reg < 4; ++reg) {
            float v = fmaxf(av[reg] + bv, 0.f);
            A_l[r0 + quad * 4 + reg][c * 16 + m] = f2bf(v);
        }
    }
    __syncthreads();

    if (out16) {
#pragma unroll
        for (int i = 0; i < 2; ++i) {
            int ch = tid + i * 256;
            int r = ch >> 3, c = ch & 7;
            int row = blk * 64 + r;
            if (row < N)
                ((uint4*)(out16 + (size_t)row * FEAT))[c] = *(const uint4*)&A_l[r][c * 8];
        }
    }

    if (wl) {
        int r = tid >> 2, part = tid & 3;
        int row = blk * 64 + r;
        if (row < N) {
            float p0 = 0.f, p1 = 0.f;
#pragma unroll
            for (int j = 0; j < 16; ++j) {
                int f = part * 16 + j;
                float v = bflo2f(A_l[r][f]);
                p0 += v * wl[f * 2 + 0];
                p1 += v * wl[f * 2 + 1];
            }
            p0 += __shfl_down(p0, 2, 4); p0 += __shfl_down(p0, 1, 4);
            p1 += __shfl_down(p1, 2, 4); p1 += __shfl_down(p1, 1, 4);
            if (part == 0) {
                p0 += bl[0];
                p1 += bl[1];
                if (flags[0]) {
                    unsigned int o = ((unsigned int)f2bf(p1) << 16) | (unsigned int)f2bf(p0);
                    ((unsigned int*)out_final)[row] = o;
                } else {
                    ((float2*)out_final)[row] = make_float2(p0, p1);
                }
            }
        }
    }
}

extern "C" void kernel_launch(void* const* d_in, const int* in_sizes, int n_in,
                              void* d_out, int out_size, void* d_ws, size_t ws_size,
                              hipStream_t stream) {
    const void* x_in = d_in[0];
    const int*  ei32 = (const int*)d_in[1];

    int N = in_sizes[0] / FEAT;
    int E = in_sizes[1] / 2;
    int NB = (N + 255) >> 8;
    int EC = (E + CHUNK - 1) / CHUNK;
    int HN = NB * EC;
    int sB = (HN + 2047) / 2048;

    // workspace layout
    unsigned short* x16   = (unsigned short*)d_ws;                 // N*64 bf16
    unsigned short* h16   = x16 + (size_t)N * FEAT;                // N*64
    unsigned short* Wt    = h16 + (size_t)N * FEAT;                // 16384
    float*          wbuf  = (float*)(Wt + 16384);                  // 16704
    int*            hist  = (int*)(wbuf + 16704);                  // HN
    int*            hscan = hist + HN;                             // HN
    int*            bsum  = hscan + HN;                            // <=512
    int*            bflag = bsum + 512;                            // <=512
    int*            flags = bflag + 512;                           // 16
    int*            offs  = flags + 16;                            // N
    int*            cnt   = offs + N;                              // N
    int*            bkt   = cnt + N;                               // E
    int*            srcs  = bkt + E;                               // E

    float* b1_32 = wbuf + 8192;
    float* b2_32 = wbuf + 16448;
    float* wl32  = wbuf + 16512;
    float* bl32  = wbuf + 16640;

    // 0. prep + P1 merged (role-split grid); block 0 zeroes scan flags
    int n8 = N * FEAT / 8;
    int pBlocks = (n8 + 255) / 256;
    if (pBlocks < 66) pBlocks = 66;
    prep_p1_kernel<<<pBlocks + EC, 256, 0, stream>>>(
        (const unsigned short*)x_in, ei32,
        d_in[2], d_in[3], d_in[4], d_in[5], d_in[6], d_in[7], d_in[8], d_in[9],
        wbuf, Wt, flags, x_in, x16, n8,
        hist, bflag, sB, E, N, NB, EC, pBlocks);

    // 1. single-pass scan (decoupled lookback) -> scatter -> finalize
    scan_kernel<<<sB, 256, 0, stream>>>(hist, hscan, bsum, bflag, HN);
    p3_scatter_kernel<<<EC, 256, 0, stream>>>(ei32, hscan, bkt, E, N, NB, EC, flags);
    p4_build_kernel<<<NB, 256, 0, stream>>>(bkt, hscan, hist, offs, cnt, srcs, E, N, NB, EC);

    int gBlocks = (N + 63) / 64;

    // 2. layer 1: fused aggregate + GEMM (x -> h16)
    sage_fused_kernel<<<gBlocks, 256, 0, stream>>>(
        x_in, x16, srcs, offs, cnt, Wt, b1_32, h16, N,
        nullptr, nullptr, nullptr, flags, 1);

    // 3. layer 2: fused aggregate + GEMM + final projection
    sage_fused_kernel<<<gBlocks, 256, 0, stream>>>(
        h16, h16, srcs, offs, cnt, Wt + 8192, b2_32, nullptr, N,
        wl32, bl32, d_out, flags, 0);
}

// Round 9
// 230.800 us; speedup vs baseline: 2.2178x; 1.0559x over previous
//
#include <hip/hip_runtime.h>
#include <hip/hip_bf16.h>

#define FEAT 64
#define CHUNK 2048   // edges per P1/P3 chunk (782 blocks ~ 3/CU) — measured best (R5)
#define MAX_NB 1024  // max buckets (256 nodes/bucket -> N <= 262144)

typedef __attribute__((ext_vector_type(8))) short bf16x8;
typedef __attribute__((ext_vector_type(4))) float f32x4;
typedef __attribute__((ext_vector_type(2))) float f32x2;

// ---------- bf16 helpers ----------
__device__ __forceinline__ float bflo2f(unsigned int u) {
    union { unsigned int u; float f; } v; v.u = u << 16; return v.f;
}
__device__ __forceinline__ float bfhi2f(unsigned int u) {
    union { unsigned int u; float f; } v; v.u = u & 0xffff0000u; return v.f;
}
__device__ __forceinline__ unsigned short f2bf(float f) {
    union { float f; unsigned int u; } v; v.f = f;
    unsigned int u = v.u;
    u += 0x7fffu + ((u >> 16) & 1u);   // round-to-nearest-even
    return (unsigned short)(u >> 16);
}
__device__ __forceinline__ f32x2 bfpair(unsigned int u) {
    f32x2 r; r.x = bflo2f(u & 0xffffu); r.y = bfhi2f(u); return r;
}

// ---------- 0. prep + P1 merged: role-split grid ----------
// blocks [0, pB): dtype detect + weight conversion + x conversion
// blocks [pB, pB+EC): per-chunk bucket histogram (bucket = dst >> 8)
__global__ __launch_bounds__(256) void prep_p1_kernel(
    const unsigned short* __restrict__ xh, const int* __restrict__ ei32,
    const void* __restrict__ w1a, const void* __restrict__ w1r,
    const void* __restrict__ b1,  const void* __restrict__ w2a,
    const void* __restrict__ w2r, const void* __restrict__ b2,
    const void* __restrict__ wl,  const void* __restrict__ bl,
    float* __restrict__ wbuf, unsigned short* __restrict__ Wt,
    int* __restrict__ flags, const void* __restrict__ x_in,
    unsigned short* __restrict__ x16, int n8,
    int* __restrict__ hist, int E, int N, int NB, int EC, int pB) {
    __shared__ int lh[MAX_NB];
    __shared__ int cnt_bf, cnt_nz;
    int tid = threadIdx.x;

    if (blockIdx.x >= pB) {
        // ---- P1 role: histogram of chunk c (self-detect int64) ----
        int c = blockIdx.x - pB;
        if (tid == 0) cnt_nz = 0;
        for (int i = tid; i < NB; i += 256) lh[i] = 0;
        __syncthreads();
        if (ei32[tid * 2 + 1] != 0) atomicAdd(&cnt_nz, 1);
        __syncthreads();
        int idx64 = (cnt_nz < 8) ? 1 : 0;
        long base = (long)c * CHUNK;
#pragma unroll 4
        for (int j = 0; j < CHUNK / 256; ++j) {
            long e = base + j * 256 + tid;
            if (e < E) {
                int d = idx64 ? ei32[2 * ((long)E + e)] : ei32[(long)E + e];
                if ((unsigned)d < (unsigned)N)
                    atomicAdd(&lh[d >> 8], 1);
            }
        }
        __syncthreads();
        for (int k = tid; k < NB; k += 256) hist[(long)k * EC + c] = lh[k];
        return;
    }

    // ---- prep role ----
    if (tid == 0) { cnt_bf = 0; cnt_nz = 0; }
    __syncthreads();
    unsigned short h = xh[tid * 2];
    int e = (h >> 7) & 0xFF;
    if (e >= 110 && e <= 132) atomicAdd(&cnt_bf, 1);
    if (ei32[tid * 2 + 1] != 0) atomicAdd(&cnt_nz, 1);
    __syncthreads();
    int f0 = (cnt_bf >= 128) ? 1 : 0;
    if (blockIdx.x == 0 && tid == 0) {
        flags[0] = f0;
        flags[1] = (cnt_nz < 8) ? 1 : 0;
    }
    int i = blockIdx.x * 256 + tid;
    // weights (blocks 0..65): wbuf f32 + Wt bf16-transposed
    if (i < 16642) {
        const void* src; int off;
        if      (i < 4096)  { src = w1a; off = i; }
        else if (i < 8192)  { src = w1r; off = i - 4096; }
        else if (i < 8256)  { src = b1;  off = i - 8192; }
        else if (i < 12352) { src = w2a; off = i - 8256; }
        else if (i < 16448) { src = w2r; off = i - 12352; }
        else if (i < 16512) { src = b2;  off = i - 16448; }
        else if (i < 16640) { src = wl;  off = i - 16512; }
        else                { src = bl;  off = i - 16640; }
        float v = f0 ? bflo2f(((const unsigned short*)src)[off])
                     : ((const float*)src)[off];
        wbuf[i] = v;
        unsigned short hv = f2bf(v);   // exact round-trip when input was bf16
        if (i < 4096)                      Wt[(off & 63) * 128 + (off >> 6)] = hv;
        else if (i < 8192)                 Wt[(off & 63) * 128 + 64 + (off >> 6)] = hv;
        else if (i >= 8256 && i < 12352)   Wt[8192 + (off & 63) * 128 + (off >> 6)] = hv;
        else if (i >= 12352 && i < 16448)  Wt[8192 + (off & 63) * 128 + 64 + (off >> 6)] = hv;
    }
    // x -> bf16 (fp32 path only)
    if (!f0 && i < n8) {
        float4 a = ((const float4*)x_in)[2 * i];
        float4 b = ((const float4*)x_in)[2 * i + 1];
        uint4 o;
        o.x = (unsigned int)f2bf(a.x) | ((unsigned int)f2bf(a.y) << 16);
        o.y = (unsigned int)f2bf(a.z) | ((unsigned int)f2bf(a.w) << 16);
        o.z = (unsigned int)f2bf(b.x) | ((unsigned int)f2bf(b.y) << 16);
        o.w = (unsigned int)f2bf(b.z) | ((unsigned int)f2bf(b.w) << 16);
        ((uint4*)x16)[i] = o;
    }
}

// ---------- scan: multi-block scan1 + scan3 ----------
__global__ __launch_bounds__(256) void scan1_kernel(const int* __restrict__ in,
                                                    int* __restrict__ out,
                                                    int* __restrict__ blocksum, int n) {
    int tid = threadIdx.x;
    int base = blockIdx.x * 2048 + tid * 8;
    int v[8];
    int tsum = 0;
#pragma unroll
    for (int i = 0; i < 8; ++i) {
        v[i] = (base + i < n) ? in[base + i] : 0;
        tsum += v[i];
    }
    int lane = tid & 63;
    int x = tsum;
#pragma unroll
    for (int off = 1; off < 64; off <<= 1) {
        int y = __shfl_up(x, off);
        if (lane >= off) x += y;
    }
    __shared__ int wsum[4];
    int wave = tid >> 6;
    if (lane == 63) wsum[wave] = x;
    __syncthreads();
    int woff = 0;
#pragma unroll
    for (int w = 0; w < 4; ++w) if (w < wave) woff += wsum[w];
    int run = woff + x - tsum;
#pragma unroll
    for (int i = 0; i < 8; ++i) {
        if (base + i < n) out[base + i] = run;
        run += v[i];
    }
    if (tid == 255) blocksum[blockIdx.x] = woff + x;
}

// scan3: block bb owns [bb*2048, +2048) -> uniform prefix via one LDS reduce.
__global__ __launch_bounds__(256) void scan3_kernel(int* __restrict__ out,
                                                    const int* __restrict__ blocksum, int n) {
    int bb = blockIdx.x, tid = threadIdx.x;
    __shared__ int wsum[4];
    __shared__ int spre;
    int s = 0;
    for (int b = tid; b < bb; b += 256) s += blocksum[b];
#pragma unroll
    for (int off = 32; off > 0; off >>= 1) s += __shfl_down(s, off);
    int lane = tid & 63, wave = tid >> 6;
    if (lane == 0) wsum[wave] = s;
    __syncthreads();
    if (tid == 0) spre = wsum[0] + wsum[1] + wsum[2] + wsum[3];
    __syncthreads();
    int pre = spre;
    int base = bb * 2048;
#pragma unroll
    for (int k = 0; k < 8; ++k) {
        int i = base + k * 256 + tid;
        if (i < n) out[i] += pre;
    }
}

// ---------- P3: scatter packed edges into bucket-major order ----------
// packed = src | ((dst & 255) << 20)   (requires N < 2^20)
__global__ __launch_bounds__(256) void p3_scatter_kernel(
    const int* __restrict__ ei32, const int* __restrict__ hscan,
    int* __restrict__ bkt, int E, int N, int NB, int EC,
    const int* __restrict__ flags) {
    __shared__ int lh[MAX_NB];
    int tid = threadIdx.x, c = blockIdx.x;
    for (int i = tid; i < NB; i += 256) lh[i] = 0;
    __syncthreads();
    int idx64 = flags[1];
    long base = (long)c * CHUNK;
#pragma unroll 4
    for (int j = 0; j < CHUNK / 256; ++j) {
        long e = base + j * 256 + tid;
        if (e < E) {
            int s = idx64 ? ei32[2 * e]             : ei32[e];
            int d = idx64 ? ei32[2 * ((long)E + e)] : ei32[(long)E + e];
            if ((unsigned)d < (unsigned)N) {
                if ((unsigned)s >= (unsigned)N) s = 0;   // clamp (memory safety)
                int k = d >> 8;
                int r = atomicAdd(&lh[k], 1);
                bkt[hscan[(long)k * EC + c] + r] = s | ((d & 255) << 20);
            }
        }
    }
}

// ---------- P4: per-bucket CSR finalize ----------
__global__ __launch_bounds__(256) void p4_build_kernel(
    const int* __restrict__ bkt, const int* __restrict__ hscan, const int* __restrict__ hist,
    int* __restrict__ offs, int* __restrict__ cnt, int* __restrict__ srcs,
    int E, int N, int NB, int EC) {
    int k = blockIdx.x, tid = threadIdx.x;
    int start = hscan[(long)k * EC];
    int end = (k + 1 < NB) ? hscan[(long)(k + 1) * EC]
                           : (hscan[(long)NB * EC - 1] + hist[(long)NB * EC - 1]);
    __shared__ int lc[256], lheads[256], wsum[4];
    lc[tid] = 0;
    __syncthreads();
    for (int e = start + tid; e < end; e += 256)
        atomicAdd(&lc[(bkt[e] >> 20) & 255], 1);
    __syncthreads();
    int cv = lc[tid];
    int lane = tid & 63, wave = tid >> 6;
    int x = cv;
#pragma unroll
    for (int off = 1; off < 64; off <<= 1) {
        int y = __shfl_up(x, off);
        if (lane >= off) x += y;
    }
    if (lane == 63) wsum[wave] = x;
    __syncthreads();
    int woff = 0;
#pragma unroll
    for (int w = 0; w < 4; ++w) if (w < wave) woff += wsum[w];
    int excl = woff + x - cv;
    int gnode = k * 256 + tid;
    if (gnode < N) { offs[gnode] = start + excl; cnt[gnode] = cv; }
    lheads[tid] = excl;
    __syncthreads();
    for (int e = start + tid; e < end; e += 256) {
        int p = bkt[e];
        int d8 = (p >> 20) & 255;
        int pos = start + atomicAdd(&lheads[d8], 1);
        srcs[pos] = p & 0xFFFFF;
    }
}

// ---------- 5+6 FUSED: aggregate + MFMA SAGE GEMM (one block = 64 nodes) ----------
// Measured-best structure (R5, 47.2 us): R1 gather (single node per 8-lane
// group, srcs global broadcast, unroll-4) + root half read directly from
// global in the MFMA loop (no root staging; A_l [64][72]; LDS 26624 B).
// Gather is pinned at the random-128B-row memory-system floor (~82 MB
// L2-miss / layer at ~1.8 TB/s) — invariant across R1/R2/R4/R5 variants.
__global__ __launch_bounds__(256) void sage_fused_kernel(
    const void* __restrict__ feat_raw, const unsigned short* __restrict__ feat_ws,
    const int* __restrict__ srcs, const int* __restrict__ offs,
    const int* __restrict__ cnt,
    const unsigned short* __restrict__ Wt, const float* __restrict__ bias,
    unsigned short* __restrict__ out16, int N,
    const float* __restrict__ wl, const float* __restrict__ bl,
    void* __restrict__ out_final, const int* __restrict__ flags, int sel) {

    // sel=1 (layer 1): bf16 input -> read x_in directly, else converted x16.
    // sel=0 (layer 2): feat_raw == feat_ws == h16.
    const unsigned short* feat16 =
        (sel && !flags[0]) ? feat_ws : (const unsigned short*)feat_raw;

    __shared__ unsigned short A_l[64][72];    // agg half only; reused as C staging
    __shared__ unsigned short B_l[64][136];   // Wt[n][k]

    int tid = threadIdx.x;
    int blk = blockIdx.x;

    // stage B: 1024 chunks of 8 shorts (B is 64 rows x 128 k)
#pragma unroll
    for (int i = 0; i < 4; ++i) {
        int ch = tid + i * 256;
        int n = ch >> 4, kc = ch & 15;
        *(uint4*)&B_l[n][kc * 8] = *(const uint4*)(Wt + n * 128 + kc * 8);
    }

    int lane = tid & 63;
    int wave = tid >> 6;
    int g = lane >> 3;
    int li = lane & 7;

    // gather-aggregate into A_l cols 0..63 (2 passes of 32 nodes)
    for (int pass = 0; pass < 2; ++pass) {
        int r = pass * 32 + wave * 8 + g;
        int node = blk * 64 + r;
        f32x2 a0 = {0.f, 0.f}, a1 = a0, a2 = a0, a3 = a0;
        int deg = 0;
        if (node < N) {
            int start = offs[node];
            deg = cnt[node];
            int j = 0;
            for (; j + 4 <= deg; j += 4) {
                int s0 = srcs[start + j];
                int s1 = srcs[start + j + 1];
                int s2 = srcs[start + j + 2];
                int s3 = srcs[start + j + 3];
                uint4 u0 = *(const uint4*)(feat16 + (size_t)s0 * FEAT + 8 * li);
                uint4 u1 = *(const uint4*)(feat16 + (size_t)s1 * FEAT + 8 * li);
                uint4 u2 = *(const uint4*)(feat16 + (size_t)s2 * FEAT + 8 * li);
                uint4 u3 = *(const uint4*)(feat16 + (size_t)s3 * FEAT + 8 * li);
                a0 += bfpair(u0.x); a1 += bfpair(u0.y); a2 += bfpair(u0.z); a3 += bfpair(u0.w);
                a0 += bfpair(u1.x); a1 += bfpair(u1.y); a2 += bfpair(u1.z); a3 += bfpair(u1.w);
                a0 += bfpair(u2.x); a1 += bfpair(u2.y); a2 += bfpair(u2.z); a3 += bfpair(u2.w);
                a0 += bfpair(u3.x); a1 += bfpair(u3.y); a2 += bfpair(u3.z); a3 += bfpair(u3.w);
            }
            for (; j < deg; ++j) {
                int s = srcs[start + j];
                uint4 u = *(const uint4*)(feat16 + (size_t)s * FEAT + 8 * li);
                a0 += bfpair(u.x); a1 += bfpair(u.y); a2 += bfpair(u.z); a3 += bfpair(u.w);
            }
        }
        float inv = 1.0f / (float)(deg > 0 ? deg : 1);
        uint4 o;
        o.x = (unsigned)f2bf(a0.x * inv) | ((unsigned)f2bf(a0.y * inv) << 16);
        o.y = (unsigned)f2bf(a1.x * inv) | ((unsigned)f2bf(a1.y * inv) << 16);
        o.z = (unsigned)f2bf(a2.x * inv) | ((unsigned)f2bf(a2.y * inv) << 16);
        o.w = (unsigned)f2bf(a3.x * inv) | ((unsigned)f2bf(a3.y * inv) << 16);
        *(uint4*)&A_l[r][8 * li] = o;
    }
    __syncthreads();

    int r0 = wave * 16;
    int m = lane & 15, quad = lane >> 4;

    // root row for the k0>=64 fragments: direct global load, clamped (rows >= N
    // produce don't-care C rows that are never stored, but must not fault)
    int arow = blk * 64 + r0 + m;
    if (arow >= N) arow = 0;
    const unsigned short* rootp = feat16 + (size_t)arow * FEAT + quad * 8;

    f32x4 acc0 = {0.f, 0.f, 0.f, 0.f};
    f32x4 acc1 = acc0, acc2 = acc0, acc3 = acc0;

#pragma unroll
    for (int k0 = 0; k0 < 128; k0 += 32) {
        bf16x8 a;
        if (k0 < 64) a = *(const bf16x8*)&A_l[r0 + m][k0 + quad * 8];
        else         a = *(const bf16x8*)(rootp + (k0 - 64));
        bf16x8 b0 = *(const bf16x8*)&B_l[ 0 + m][k0 + quad * 8];
        bf16x8 b1 = *(const bf16x8*)&B_l[16 + m][k0 + quad * 8];
        bf16x8 b2 = *(const bf16x8*)&B_l[32 + m][k0 + quad * 8];
        bf16x8 b3 = *(const bf16x8*)&B_l[48 + m][k0 + quad * 8];
        acc0 = __builtin_amdgcn_mfma_f32_16x16x32_bf16(a, b0, acc0, 0, 0, 0);
        acc1 = __builtin_amdgcn_mfma_f32_16x16x32_bf16(a, b1, acc1, 0, 0, 0);
        acc2 = __builtin_amdgcn_mfma_f32_16x16x32_bf16(a, b2, acc2, 0, 0, 0);
        acc3 = __builtin_amdgcn_mfma_f32_16x16x32_bf16(a, b3, acc3, 0, 0, 0);
    }
    __syncthreads();   // done reading A_l; reuse as C staging

    // epilogue: +bias, relu, bf16 -> A_l[row][col]  (C/D: col=lane&15, row=quad*4+reg)
#pragma unroll
    for (int c = 0; c < 4; ++c) {
        f32x4 av = (c == 0) ? acc0 : (c == 1) ? acc1 : (c == 2) ? acc2 : acc3;
        float bv = bias[c * 16 + m];
#pragma unroll
        for (int reg = 0; reg < 4; ++reg) {
            float v = fmaxf(av[reg] + bv, 0.f);
            A_l[r0 + quad * 4 + reg][c * 16 + m] = f2bf(v);
        }
    }
    __syncthreads();

    // coalesced store of C rows (layer 1 only): 512 uint4 chunks
    if (out16) {
#pragma unroll
        for (int i = 0; i < 2; ++i) {
            int ch = tid + i * 256;
            int r = ch >> 3, c = ch & 7;
            int row = blk * 64 + r;
            if (row < N)
                ((uint4*)(out16 + (size_t)row * FEAT))[c] = *(const uint4*)&A_l[r][c * 8];
        }
    }

    // fused final projection (layer 2): 4 threads per row, 16 feats each
    if (wl) {
        int r = tid >> 2, part = tid & 3;
        int row = blk * 64 + r;
        if (row < N) {
            float p0 = 0.f, p1 = 0.f;
#pragma unroll
            for (int j = 0; j < 16; ++j) {
                int f = part * 16 + j;
                float v = bflo2f(A_l[r][f]);
                p0 += v * wl[f * 2 + 0];
                p1 += v * wl[f * 2 + 1];
            }
            p0 += __shfl_down(p0, 2, 4); p0 += __shfl_down(p0, 1, 4);
            p1 += __shfl_down(p1, 2, 4); p1 += __shfl_down(p1, 1, 4);
            if (part == 0) {
                p0 += bl[0];
                p1 += bl[1];
                if (flags[0]) {
                    unsigned int o = ((unsigned int)f2bf(p1) << 16) | (unsigned int)f2bf(p0);
                    ((unsigned int*)out_final)[row] = o;
                } else {
                    ((float2*)out_final)[row] = make_float2(p0, p1);
                }
            }
        }
    }
}

extern "C" void kernel_launch(void* const* d_in, const int* in_sizes, int n_in,
                              void* d_out, int out_size, void* d_ws, size_t ws_size,
                              hipStream_t stream) {
    const void* x_in = d_in[0];
    const int*  ei32 = (const int*)d_in[1];

    int N = in_sizes[0] / FEAT;
    int E = in_sizes[1] / 2;
    int NB = (N + 255) >> 8;
    int EC = (E + CHUNK - 1) / CHUNK;
    int HN = NB * EC;

    // workspace layout
    unsigned short* x16   = (unsigned short*)d_ws;                 // N*64 bf16
    unsigned short* h16   = x16 + (size_t)N * FEAT;                // N*64
    unsigned short* Wt    = h16 + (size_t)N * FEAT;                // 16384
    float*          wbuf  = (float*)(Wt + 16384);                  // 16704
    int*            hist  = (int*)(wbuf + 16704);                  // HN
    int*            hscan = hist + HN;                             // HN
    int*            bsum  = hscan + HN;                            // <=1024
    int*            flags = bsum + 1024;                           // 16
    int*            offs  = flags + 16;                            // N
    int*            cnt   = offs + N;                              // N
    int*            bkt   = cnt + N;                               // E
    int*            srcs  = bkt + E;                               // E

    float* b1_32 = wbuf + 8192;
    float* b2_32 = wbuf + 16448;
    float* wl32  = wbuf + 16512;
    float* bl32  = wbuf + 16640;

    // 0. prep + P1 merged (role-split grid)
    int n8 = N * FEAT / 8;
    int pBlocks = (n8 + 255) / 256;
    if (pBlocks < 66) pBlocks = 66;
    prep_p1_kernel<<<pBlocks + EC, 256, 0, stream>>>(
        (const unsigned short*)x_in, ei32,
        d_in[2], d_in[3], d_in[4], d_in[5], d_in[6], d_in[7], d_in[8], d_in[9],
        wbuf, Wt, flags, x_in, x16, n8,
        hist, E, N, NB, EC, pBlocks);

    // 1. scan -> scatter -> finalize
    int sB = (HN + 2047) / 2048;
    scan1_kernel<<<sB, 256, 0, stream>>>(hist, hscan, bsum, HN);
    scan3_kernel<<<sB, 256, 0, stream>>>(hscan, bsum, HN);
    p3_scatter_kernel<<<EC, 256, 0, stream>>>(ei32, hscan, bkt, E, N, NB, EC, flags);
    p4_build_kernel<<<NB, 256, 0, stream>>>(bkt, hscan, hist, offs, cnt, srcs, E, N, NB, EC);

    int gBlocks = (N + 63) / 64;

    // 2. layer 1: fused aggregate + GEMM (x -> h16)
    sage_fused_kernel<<<gBlocks, 256, 0, stream>>>(
        x_in, x16, srcs, offs, cnt, Wt, b1_32, h16, N,
        nullptr, nullptr, nullptr, flags, 1);

    // 3. layer 2: fused aggregate + GEMM + final projection
    sage_fused_kernel<<<gBlocks, 256, 0, stream>>>(
        h16, h16, srcs, offs, cnt, Wt + 8192, b2_32, nullptr, N,
        wl32, bl32, d_out, flags, 0);
}